// Round 2
// baseline (226.336 us; speedup 1.0000x reference)
//
#include <hip/hip_runtime.h>
#include <math.h>

#define NB       1025
#define M        1024      // half-length complex FFT size
#define FFTN     2048
#define HOP      512
#define NFRAMES  4000
#define BATCH    4
#define OUT_T    2047488   // (F-1)*hop + N - 2*half
#define PI_F     3.14159265358979323846f

__device__ __forceinline__ float2 cmul(float2 a, float2 b) {
    return make_float2(a.x*b.x - a.y*b.y, a.x*b.y + a.y*b.x);
}

// XOR swizzle: bijective on [0,1024), spreads strided float2 accesses across
// bank pairs (float2 bank-pair = index mod 16; low 4 bits ^= bits 4..7).
__device__ __forceinline__ int SW(int i) { return i ^ ((i >> 4) & 15); }

// window_sumsquare at trimmed output position p (boundary version, <=4 terms)
__device__ __forceinline__ float wsq_at(int p) {
    int u  = p + FFTN / 2;     // untrimmed position
    int fm = u >> 9;
    int n0 = u & 511;
    float wsq = 0.f;
    #pragma unroll
    for (int jj = 0; jj < 4; ++jj) {
        int fr = fm - jj;
        if (fr >= 0 && fr < NFRAMES) {
            int n = n0 + (jj << 9);
            float sw = __sinf((PI_F / (float)FFTN) * (float)n);
            float w  = sw * sw;
            wsq += w * w;
        }
    }
    const float tiny = 1.17549435e-38f;
    return (wsq > tiny) ? wsq : 1.0f;
}

// One block per frame: pack Hermitian spectrum into 1024-pt complex seq,
// radix-4 Stockham IFFT (stages 0..3 via swizzled LDS, stage 4 in registers),
// then window + 1/wsq + atomic overlap-add straight from registers.
__global__ __launch_bounds__(256) void istft_fft_kernel(
    const float* __restrict__ sr, const float* __restrict__ si,
    float* __restrict__ out)
{
    __shared__ float2 bufA[M];
    __shared__ float2 bufB[M];

    const int blk = blockIdx.x;
    const int b   = blk / NFRAMES;
    const int f   = blk - b * NFRAMES;
    const float* __restrict__ xr = sr + (size_t)blk * NB;
    const float* __restrict__ xi = si + (size_t)blk * NB;
    const int j = threadIdx.x;

    // ---- Build Z[k] = E[k] + i*O[k]
    #pragma unroll
    for (int kk = 0; kk < 4; ++kk) {
        int k = j + kk * 256;
        float ar = xr[k],  ai = xi[k];
        int   mk = M - k;
        float br = xr[mk], bi = xi[mk];
        if (k == 0) { ai = 0.f; bi = 0.f; }
        float Er = 0.5f * (ar + br);
        float Ei = 0.5f * (ai - bi);
        float Dr = 0.5f * (ar - br);
        float Di = 0.5f * (ai + bi);
        float s, c;
        __sincosf(PI_F * (float)k * (1.0f / (float)M), &s, &c);
        float Or = Dr * c - Di * s;
        float Oi = Dr * s + Di * c;
        bufA[SW(k)] = make_float2(Er - Oi, Ei + Or);
    }
    __syncthreads();

    // ---- stages 0..3 in LDS (swizzled), stage 4 in registers
    float2* src = bufA;
    float2* dst = bufB;
    #pragma unroll
    for (int st = 0; st < 4; ++st) {
        const int Ns = 1 << (2 * st);
        float2 v0 = src[SW(j)];
        float2 v1 = src[SW(j + 256)];
        float2 v2 = src[SW(j + 512)];
        float2 v3 = src[SW(j + 768)];
        int jm = j & (Ns - 1);
        float ang = (0.5f * PI_F / (float)Ns) * (float)jm;
        float s1, c1;
        __sincosf(ang, &s1, &c1);
        float2 w1 = make_float2(c1, s1);
        float2 w2 = cmul(w1, w1);
        float2 w3 = cmul(w2, w1);
        v1 = cmul(v1, w1);
        v2 = cmul(v2, w2);
        v3 = cmul(v3, w3);
        float2 t0 = make_float2(v0.x + v2.x, v0.y + v2.y);
        float2 t1 = make_float2(v0.x - v2.x, v0.y - v2.y);
        float2 t2 = make_float2(v1.x + v3.x, v1.y + v3.y);
        float2 t3 = make_float2(v1.x - v3.x, v1.y - v3.y);
        int idxD = ((j >> (2 * st)) << (2 * st + 2)) + jm;
        dst[SW(idxD         )] = make_float2(t0.x + t2.x, t0.y + t2.y);
        dst[SW(idxD +     Ns)] = make_float2(t1.x - t3.y, t1.y + t3.x);
        dst[SW(idxD + 2 * Ns)] = make_float2(t0.x - t2.x, t0.y - t2.y);
        dst[SW(idxD + 3 * Ns)] = make_float2(t1.x + t3.y, t1.y - t3.x);
        float2* tmp = src; src = dst; dst = tmp;
        __syncthreads();
    }

    // ---- stage 4 (Ns=256): outputs g[n] at n = j, j+256, j+512, j+768 in regs
    float2 v0 = src[SW(j)];
    float2 v1 = src[SW(j + 256)];
    float2 v2 = src[SW(j + 512)];
    float2 v3 = src[SW(j + 768)];
    {
        float ang = (0.5f * PI_F / 256.0f) * (float)j;
        float s1, c1;
        __sincosf(ang, &s1, &c1);
        float2 w1 = make_float2(c1, s1);
        float2 w2 = cmul(w1, w1);
        float2 w3 = cmul(w2, w1);
        v1 = cmul(v1, w1);
        v2 = cmul(v2, w2);
        v3 = cmul(v3, w3);
    }
    float2 t0 = make_float2(v0.x + v2.x, v0.y + v2.y);
    float2 t1 = make_float2(v0.x - v2.x, v0.y - v2.y);
    float2 t2 = make_float2(v1.x + v3.x, v1.y + v3.y);
    float2 t3 = make_float2(v1.x - v3.x, v1.y - v3.x * 0.f - v3.x);  // placeholder fixed below
    // (recompute cleanly to avoid mistakes)
    t3 = make_float2(v1.x - v3.x, v1.y - v3.y);
    float2 g0 = make_float2(t0.x + t2.x, t0.y + t2.y);           // n = j
    float2 g1 = make_float2(t1.x - t3.y, t1.y + t3.x);           // n = j+256
    float2 g2 = make_float2(t0.x - t2.x, t0.y - t2.y);           // n = j+512
    float2 g3 = make_float2(t1.x + t3.y, t1.y - t3.x);           // n = j+768

    // ---- window, scale, 1/wsq, atomic OLA (x[2n]=Re g, x[2n+1]=Im g)
    const float inv = 1.0f / (float)M;
    float* outb = out + (size_t)b * OUT_T;
    const int base = f * HOP - (FFTN / 2);

    float2 gv[4] = {g0, g1, g2, g3};
    #pragma unroll
    for (int q = 0; q < 4; ++q) {
        int n = j + q * 256;
        #pragma unroll
        for (int h = 0; h < 2; ++h) {
            int   t   = 2 * n + h;
            float val = h ? gv[q].y : gv[q].x;
            int   p   = base + t;
            if ((unsigned)p < (unsigned)OUT_T) {
                float swv = __sinf((PI_F / (float)FFTN) * (float)t);
                float w   = swv * swv;
                float invw;
                if (p < 512 || p >= OUT_T - 512) invw = 1.0f / wsq_at(p);
                else                              invw = (2.0f / 3.0f);
                atomicAdd(outb + p, val * w * inv * invw);
            }
        }
    }
}

extern "C" void kernel_launch(void* const* d_in, const int* in_sizes, int n_in,
                              void* d_out, int out_size, void* d_ws, size_t ws_size,
                              hipStream_t stream) {
    const float* sr = (const float*)d_in[0];
    const float* si = (const float*)d_in[1];
    float* out = (float*)d_out;

    hipMemsetAsync(d_out, 0, (size_t)out_size * sizeof(float), stream);
    istft_fft_kernel<<<BATCH * NFRAMES, 256, 0, stream>>>(sr, si, out);
}

// Round 3
// 80.757 us; speedup vs baseline: 2.8027x; 2.8027x over previous
//
#include <hip/hip_runtime.h>
#include <math.h>

#define NB       1025
#define M        1024      // half-length complex FFT size
#define FFTN     2048
#define HOP      512
#define NFRAMES  4000
#define BATCH    4
#define OUT_T    2047488   // (F-1)*hop + N - 2*half
#define R_HOPS   16
#define REG_PB   251       // ceil(4003/16); untrimmed length = 4003*512
#define ACC_N    (R_HOPS * HOP)   // 8192 floats per region
#define PI_F     3.14159265358979323846f

__device__ __forceinline__ float2 cmul(float2 a, float2 b) {
    return make_float2(a.x*b.x - a.y*b.y, a.x*b.y + a.y*b.x);
}
// float2 bank-pair swizzle — reaches the wave64 b64 floor (4 lanes/bank-pair)
__device__ __forceinline__ int SW(int i) { return i ^ ((i >> 4) & 15); }

// window_sumsquare at trimmed position p (boundary path, <=4 terms)
__device__ __forceinline__ float wsq_at(int p) {
    int u  = p + FFTN / 2;
    int fm = u >> 9;
    int n0 = u & 511;
    float wsq = 0.f;
    #pragma unroll
    for (int jj = 0; jj < 4; ++jj) {
        int fr = fm - jj;
        if (fr >= 0 && fr < NFRAMES) {
            int n = n0 + (jj << 9);
            float sw = __sinf((PI_F / (float)FFTN) * (float)n);
            float w  = sw * sw;
            wsq += w * w;
        }
    }
    const float tiny = 1.17549435e-38f;
    return (wsq > tiny) ? wsq : 1.0f;
}

template<int ST>
__device__ __forceinline__ void stage(const float2* __restrict__ src,
                                      float2* __restrict__ dst, int j,
                                      float2 w1, float2 w2, float2 w3) {
    const int Ns = 1 << (2 * ST);
    float2 v0 = src[SW(j)];
    float2 v1 = src[SW(j + 256)];
    float2 v2 = src[SW(j + 512)];
    float2 v3 = src[SW(j + 768)];
    if (ST > 0) { v1 = cmul(v1, w1); v2 = cmul(v2, w2); v3 = cmul(v3, w3); }
    float2 t0 = make_float2(v0.x + v2.x, v0.y + v2.y);
    float2 t1 = make_float2(v0.x - v2.x, v0.y - v2.y);
    float2 t2 = make_float2(v1.x + v3.x, v1.y + v3.y);
    float2 t3 = make_float2(v1.x - v3.x, v1.y - v3.y);
    int jm = j & (Ns - 1);
    int idxD = ((j >> (2 * ST)) << (2 * ST + 2)) + jm;
    dst[SW(idxD         )] = make_float2(t0.x + t2.x, t0.y + t2.y);
    dst[SW(idxD +     Ns)] = make_float2(t1.x - t3.y, t1.y + t3.x);
    dst[SW(idxD + 2 * Ns)] = make_float2(t0.x - t2.x, t0.y - t2.y);
    dst[SW(idxD + 3 * Ns)] = make_float2(t1.x + t3.y, t1.y - t3.x);
}

// One block owns R_HOPS hops of output; computes all overlapping frames'
// IFFTs, accumulates windowed samples in LDS, writes each output once.
__global__ __launch_bounds__(256) void istft_region_kernel(
    const float* __restrict__ sr, const float* __restrict__ si,
    float* __restrict__ out)
{
    __shared__ float2 bufA[M];
    __shared__ float2 bufB[M];
    __shared__ float2 acc2[ACC_N / 2];   // 32 KB accumulator

    const int blk = blockIdx.x;
    const int b   = blk / REG_PB;
    const int reg = blk - b * REG_PB;
    const int s0h = reg * R_HOPS;        // first hop-slot owned (untrimmed)
    const int j   = threadIdx.x;

    // zero accumulator
    #pragma unroll
    for (int q = 0; q < ACC_N / 2 / 256; ++q)
        acc2[j + q * 256] = make_float2(0.f, 0.f);

    // ---- per-block precompute (reused across all frames) ----
    float2 tw_pack[4];
    #pragma unroll
    for (int kk = 0; kk < 4; ++kk) {
        int k = j + kk * 256;
        float s, c;
        __sincosf(PI_F * (float)k * (1.0f / (float)M), &s, &c);
        tw_pack[kk] = make_float2(c, s);
    }
    float2 w1s[4], w2s[4], w3s[4];       // stages 1..4, fully unrolled (static idx)
    #pragma unroll
    for (int st = 1; st <= 4; ++st) {
        int Ns = 1 << (2 * st);
        int jm = j & (Ns - 1);
        float ang = (0.5f * PI_F / (float)Ns) * (float)jm;
        float s1, c1;
        __sincosf(ang, &s1, &c1);
        float2 w1 = make_float2(c1, s1);
        w1s[st-1] = w1;
        w2s[st-1] = cmul(w1, w1);
        w3s[st-1] = cmul(w2s[st-1], w1);
    }
    float wreg[4][2];                    // hann^1(t)/M for t = 2n, 2n+1
    #pragma unroll
    for (int q = 0; q < 4; ++q) {
        int n = j + q * 256;
        #pragma unroll
        for (int h = 0; h < 2; ++h) {
            int t = 2 * n + h;
            float swv = __sinf((PI_F / (float)FFTN) * (float)t);
            wreg[q][h] = swv * swv * (1.0f / (float)M);
        }
    }

    int f0 = s0h - 3;           if (f0 < 0)            f0 = 0;
    int f1 = s0h + R_HOPS - 1;  if (f1 > NFRAMES - 1)  f1 = NFRAMES - 1;

    __syncthreads();   // acc zeroed

    for (int f = f0; f <= f1; ++f) {
        const float* __restrict__ xr = sr + ((size_t)b * NFRAMES + f) * NB;
        const float* __restrict__ xi = si + ((size_t)b * NFRAMES + f) * NB;

        // pack Hermitian spectrum -> 1024-pt complex sequence
        #pragma unroll
        for (int kk = 0; kk < 4; ++kk) {
            int k = j + kk * 256;
            float ar = xr[k],  ai = xi[k];
            int   mk = M - k;
            float br = xr[mk], bi = xi[mk];
            if (k == 0) { ai = 0.f; bi = 0.f; }
            float Er = 0.5f * (ar + br);
            float Ei = 0.5f * (ai - bi);
            float Dr = 0.5f * (ar - br);
            float Di = 0.5f * (ai + bi);
            float2 t = tw_pack[kk];
            float Or = Dr * t.x - Di * t.y;
            float Oi = Dr * t.y + Di * t.x;
            bufA[SW(k)] = make_float2(Er - Oi, Ei + Or);
        }
        __syncthreads();
        stage<0>(bufA, bufB, j, w1s[0], w1s[0], w1s[0]);  // twiddles unused
        __syncthreads();
        stage<1>(bufB, bufA, j, w1s[0], w2s[0], w3s[0]);
        __syncthreads();
        stage<2>(bufA, bufB, j, w1s[1], w2s[1], w3s[1]);
        __syncthreads();
        stage<3>(bufB, bufA, j, w1s[2], w2s[2], w3s[2]);
        __syncthreads();

        // stage 4 in registers: g at n = j, j+256, j+512, j+768
        float2 v0 = bufA[SW(j)];
        float2 v1 = bufA[SW(j + 256)];
        float2 v2 = bufA[SW(j + 512)];
        float2 v3 = bufA[SW(j + 768)];
        v1 = cmul(v1, w1s[3]);
        v2 = cmul(v2, w2s[3]);
        v3 = cmul(v3, w3s[3]);
        float2 t0 = make_float2(v0.x + v2.x, v0.y + v2.y);
        float2 t1 = make_float2(v0.x - v2.x, v0.y - v2.y);
        float2 t2 = make_float2(v1.x + v3.x, v1.y + v3.y);
        float2 t3 = make_float2(v1.x - v3.x, v1.y - v3.y);
        float2 g0 = make_float2(t0.x + t2.x, t0.y + t2.y);   // n = j
        float2 g1 = make_float2(t1.x - t3.y, t1.y + t3.x);   // n = j+256
        float2 g2 = make_float2(t0.x - t2.x, t0.y - t2.y);   // n = j+512
        float2 g3 = make_float2(t1.x + t3.y, t1.y - t3.x);   // n = j+768

        // windowed accumulate into region acc (x[2n]=Re g, x[2n+1]=Im g)
        int ofs2 = (HOP / 2) * (f - s0h);                    // float2 index offset
        {
            int i2 = ofs2 + j;
            if ((unsigned)i2 < (unsigned)(ACC_N / 2)) {
                float2 a = acc2[i2];
                a.x += g0.x * wreg[0][0];  a.y += g0.y * wreg[0][1];
                acc2[i2] = a;
            }
            i2 = ofs2 + j + 256;
            if ((unsigned)i2 < (unsigned)(ACC_N / 2)) {
                float2 a = acc2[i2];
                a.x += g1.x * wreg[1][0];  a.y += g1.y * wreg[1][1];
                acc2[i2] = a;
            }
            i2 = ofs2 + j + 512;
            if ((unsigned)i2 < (unsigned)(ACC_N / 2)) {
                float2 a = acc2[i2];
                a.x += g2.x * wreg[2][0];  a.y += g2.y * wreg[2][1];
                acc2[i2] = a;
            }
            i2 = ofs2 + j + 768;
            if ((unsigned)i2 < (unsigned)(ACC_N / 2)) {
                float2 a = acc2[i2];
                a.x += g3.x * wreg[3][0];  a.y += g3.y * wreg[3][1];
                acc2[i2] = a;
            }
        }
        __syncthreads();   // stage-4 reads + this frame's accumulate done
    }

    // ---- epilogue: divide by window_sumsquare, write once, coalesced ----
    const float* accf = (const float*)acc2;
    const int base_u = s0h * HOP;
    float* outb = out + (size_t)b * OUT_T;
    #pragma unroll
    for (int q = 0; q < ACC_N / 256; ++q) {
        int i = j + q * 256;
        int p = base_u + i - FFTN / 2;
        if ((unsigned)p < (unsigned)OUT_T) {
            float invw;
            if (p < 512 || p >= OUT_T - 512) invw = 1.0f / wsq_at(p);
            else                             invw = (1.0f / 1.5f);
            outb[p] = accf[i] * invw;
        }
    }
}

extern "C" void kernel_launch(void* const* d_in, const int* in_sizes, int n_in,
                              void* d_out, int out_size, void* d_ws, size_t ws_size,
                              hipStream_t stream) {
    const float* sr = (const float*)d_in[0];
    const float* si = (const float*)d_in[1];
    float* out = (float*)d_out;
    istft_region_kernel<<<BATCH * REG_PB, 256, 0, stream>>>(sr, si, out);
}

// Round 4
// 75.830 us; speedup vs baseline: 2.9848x; 1.0650x over previous
//
#include <hip/hip_runtime.h>
#include <math.h>

#define NB       1025
#define M        1024      // half-length complex FFT size
#define FFTN     2048
#define HOP      512
#define NFRAMES  4000
#define BATCH    4
#define OUT_T    2047488   // (F-1)*hop + N - 2*half
#define R_HOPS   8
#define REG_PB   501       // ceil(4003/8); untrimmed length = 4003*512 + tail
#define ACC_N    (R_HOPS * HOP)   // 4096 floats per region
#define PI_F     3.14159265358979323846f

__device__ __forceinline__ float2 cmul(float2 a, float2 b) {
    return make_float2(a.x*b.x - a.y*b.y, a.x*b.y + a.y*b.x);
}
// float2 bank-pair swizzle — reaches the wave64 b64 floor (4 lanes/bank-pair)
__device__ __forceinline__ int SW(int i) { return i ^ ((i >> 4) & 15); }

// window_sumsquare at trimmed position p (boundary path, <=4 terms)
__device__ __forceinline__ float wsq_at(int p) {
    int u  = p + FFTN / 2;
    int fm = u >> 9;
    int n0 = u & 511;
    float wsq = 0.f;
    #pragma unroll
    for (int jj = 0; jj < 4; ++jj) {
        int fr = fm - jj;
        if (fr >= 0 && fr < NFRAMES) {
            int n = n0 + (jj << 9);
            float sw = __sinf((PI_F / (float)FFTN) * (float)n);
            float w  = sw * sw;
            wsq += w * w;
        }
    }
    const float tiny = 1.17549435e-38f;
    return (wsq > tiny) ? wsq : 1.0f;
}

template<int ST>
__device__ __forceinline__ void stage(const float2* __restrict__ src,
                                      float2* __restrict__ dst, int j,
                                      float2 w1, float2 w2, float2 w3) {
    const int Ns = 1 << (2 * ST);
    float2 v0 = src[SW(j)];
    float2 v1 = src[SW(j + 256)];
    float2 v2 = src[SW(j + 512)];
    float2 v3 = src[SW(j + 768)];
    if (ST > 0) { v1 = cmul(v1, w1); v2 = cmul(v2, w2); v3 = cmul(v3, w3); }
    float2 t0 = make_float2(v0.x + v2.x, v0.y + v2.y);
    float2 t1 = make_float2(v0.x - v2.x, v0.y - v2.y);
    float2 t2 = make_float2(v1.x + v3.x, v1.y + v3.y);
    float2 t3 = make_float2(v1.x - v3.x, v1.y - v3.y);
    int jm = j & (Ns - 1);
    int idxD = ((j >> (2 * ST)) << (2 * ST + 2)) + jm;
    dst[SW(idxD         )] = make_float2(t0.x + t2.x, t0.y + t2.y);
    dst[SW(idxD +     Ns)] = make_float2(t1.x - t3.y, t1.y + t3.x);
    dst[SW(idxD + 2 * Ns)] = make_float2(t0.x - t2.x, t0.y - t2.y);
    dst[SW(idxD + 3 * Ns)] = make_float2(t1.x + t3.y, t1.y - t3.x);
}

// One block owns R_HOPS hops of output; computes all overlapping frames'
// IFFTs, accumulates windowed samples in LDS, writes each output once.
__global__ __launch_bounds__(256) void istft_region_kernel(
    const float* __restrict__ sr, const float* __restrict__ si,
    float* __restrict__ out)
{
    __shared__ float2 bufA[M];
    __shared__ float2 bufB[M];
    __shared__ float2 acc2[ACC_N / 2];   // 16 KB accumulator

    const int blk = blockIdx.x;
    const int b   = blk / REG_PB;
    const int reg = blk - b * REG_PB;
    const int s0h = reg * R_HOPS;        // first hop-slot owned (untrimmed)
    const int j   = threadIdx.x;

    // zero accumulator
    #pragma unroll
    for (int q = 0; q < ACC_N / 2 / 256; ++q)
        acc2[j + q * 256] = make_float2(0.f, 0.f);

    // ---- per-block precompute (reused across all frames) ----
    float2 tw_pack[4];
    #pragma unroll
    for (int kk = 0; kk < 4; ++kk) {
        int k = j + kk * 256;
        float s, c;
        __sincosf(PI_F * (float)k * (1.0f / (float)M), &s, &c);
        tw_pack[kk] = make_float2(c, s);
    }
    float2 w1s[4], w2s[4], w3s[4];       // stages 1..4, fully unrolled (static idx)
    #pragma unroll
    for (int st = 1; st <= 4; ++st) {
        int Ns = 1 << (2 * st);
        int jm = j & (Ns - 1);
        float ang = (0.5f * PI_F / (float)Ns) * (float)jm;
        float s1, c1;
        __sincosf(ang, &s1, &c1);
        float2 w1 = make_float2(c1, s1);
        w1s[st-1] = w1;
        w2s[st-1] = cmul(w1, w1);
        w3s[st-1] = cmul(w2s[st-1], w1);
    }
    float wreg[4][2];                    // hann^1(t)/M for t = 2n, 2n+1
    #pragma unroll
    for (int q = 0; q < 4; ++q) {
        int n = j + q * 256;
        #pragma unroll
        for (int h = 0; h < 2; ++h) {
            int t = 2 * n + h;
            float swv = __sinf((PI_F / (float)FFTN) * (float)t);
            wreg[q][h] = swv * swv * (1.0f / (float)M);
        }
    }

    int f0 = s0h - 3;           if (f0 < 0)            f0 = 0;
    int f1 = s0h + R_HOPS - 1;  if (f1 > NFRAMES - 1)  f1 = NFRAMES - 1;

    __syncthreads();   // acc zeroed

    for (int f = f0; f <= f1; ++f) {
        const float* __restrict__ xr = sr + ((size_t)b * NFRAMES + f) * NB;
        const float* __restrict__ xi = si + ((size_t)b * NFRAMES + f) * NB;

        // pack Hermitian spectrum -> 1024-pt complex sequence
        #pragma unroll
        for (int kk = 0; kk < 4; ++kk) {
            int k = j + kk * 256;
            float ar = xr[k],  ai = xi[k];
            int   mk = M - k;
            float br = xr[mk], bi = xi[mk];
            if (k == 0) { ai = 0.f; bi = 0.f; }
            float Er = 0.5f * (ar + br);
            float Ei = 0.5f * (ai - bi);
            float Dr = 0.5f * (ar - br);
            float Di = 0.5f * (ai + bi);
            float2 t = tw_pack[kk];
            float Or = Dr * t.x - Di * t.y;
            float Oi = Dr * t.y + Di * t.x;
            bufA[SW(k)] = make_float2(Er - Oi, Ei + Or);
        }
        __syncthreads();
        stage<0>(bufA, bufB, j, w1s[0], w1s[0], w1s[0]);  // twiddles unused
        __syncthreads();
        stage<1>(bufB, bufA, j, w1s[0], w2s[0], w3s[0]);
        __syncthreads();
        stage<2>(bufA, bufB, j, w1s[1], w2s[1], w3s[1]);
        __syncthreads();
        stage<3>(bufB, bufA, j, w1s[2], w2s[2], w3s[2]);
        __syncthreads();

        // stage 4 in registers: g at n = j, j+256, j+512, j+768
        float2 v0 = bufA[SW(j)];
        float2 v1 = bufA[SW(j + 256)];
        float2 v2 = bufA[SW(j + 512)];
        float2 v3 = bufA[SW(j + 768)];
        v1 = cmul(v1, w1s[3]);
        v2 = cmul(v2, w2s[3]);
        v3 = cmul(v3, w3s[3]);
        float2 t0 = make_float2(v0.x + v2.x, v0.y + v2.y);
        float2 t1 = make_float2(v0.x - v2.x, v0.y - v2.y);
        float2 t2 = make_float2(v1.x + v3.x, v1.y + v3.y);
        float2 t3 = make_float2(v1.x - v3.x, v1.y - v3.y);
        float2 g0 = make_float2(t0.x + t2.x, t0.y + t2.y);   // n = j
        float2 g1 = make_float2(t1.x - t3.y, t1.y + t3.x);   // n = j+256
        float2 g2 = make_float2(t0.x - t2.x, t0.y - t2.y);   // n = j+512
        float2 g3 = make_float2(t1.x + t3.y, t1.y - t3.x);   // n = j+768

        // windowed accumulate into region acc (x[2n]=Re g, x[2n+1]=Im g)
        int ofs2 = (HOP / 2) * (f - s0h);                    // float2 index offset
        {
            int i2 = ofs2 + j;
            if ((unsigned)i2 < (unsigned)(ACC_N / 2)) {
                float2 a = acc2[i2];
                a.x += g0.x * wreg[0][0];  a.y += g0.y * wreg[0][1];
                acc2[i2] = a;
            }
            i2 = ofs2 + j + 256;
            if ((unsigned)i2 < (unsigned)(ACC_N / 2)) {
                float2 a = acc2[i2];
                a.x += g1.x * wreg[1][0];  a.y += g1.y * wreg[1][1];
                acc2[i2] = a;
            }
            i2 = ofs2 + j + 512;
            if ((unsigned)i2 < (unsigned)(ACC_N / 2)) {
                float2 a = acc2[i2];
                a.x += g2.x * wreg[2][0];  a.y += g2.y * wreg[2][1];
                acc2[i2] = a;
            }
            i2 = ofs2 + j + 768;
            if ((unsigned)i2 < (unsigned)(ACC_N / 2)) {
                float2 a = acc2[i2];
                a.x += g3.x * wreg[3][0];  a.y += g3.y * wreg[3][1];
                acc2[i2] = a;
            }
        }
        __syncthreads();   // stage-4 reads + this frame's accumulate done
    }

    // ---- epilogue: divide by window_sumsquare, write once, coalesced ----
    const float* accf = (const float*)acc2;
    const int base_u = s0h * HOP;
    float* outb = out + (size_t)b * OUT_T;
    #pragma unroll
    for (int q = 0; q < ACC_N / 256; ++q) {
        int i = j + q * 256;
        int p = base_u + i - FFTN / 2;
        if ((unsigned)p < (unsigned)OUT_T) {
            float invw;
            if (p < 512 || p >= OUT_T - 512) invw = 1.0f / wsq_at(p);
            else                             invw = (1.0f / 1.5f);
            outb[p] = accf[i] * invw;
        }
    }
}

extern "C" void kernel_launch(void* const* d_in, const int* in_sizes, int n_in,
                              void* d_out, int out_size, void* d_ws, size_t ws_size,
                              hipStream_t stream) {
    const float* sr = (const float*)d_in[0];
    const float* si = (const float*)d_in[1];
    float* out = (float*)d_out;
    istft_region_kernel<<<BATCH * REG_PB, 256, 0, stream>>>(sr, si, out);
}